// Round 1
// baseline (116.629 us; speedup 1.0000x reference)
//
#include <hip/hip_runtime.h>

#define BB 256
#define SS 2048
#define FF 64
#define NBB 32

// 2*log2(e): folded into u so the scan's tanh needs only exp2 (no extra mul on chain)
#define TWO_OVER_LN2 2.885390081777927f

// ---------------------------------------------------------------------------
// K1: u[b][t] = 2log2e * ( dot(X[b,t,:], W_ih) + b_ih + b_hh )
// 16 lanes per row (float4 each), butterfly-reduce, lane0 writes.
// Reads X fully coalesced (1 KiB per wave-load); writes coalesce per block.
// ---------------------------------------------------------------------------
__global__ __launch_bounds__(256) void k_proj(
    const float* __restrict__ X, const float* __restrict__ W_ih,
    const float* __restrict__ b_ih, const float* __restrict__ b_hh,
    float* __restrict__ u)
{
    const int lane16 = threadIdx.x & 15;
    const int group  = (blockIdx.x * blockDim.x + threadIdx.x) >> 4;
    const int ngroups = (gridDim.x * blockDim.x) >> 4;
    const float4 w = reinterpret_cast<const float4*>(W_ih)[lane16];
    const float bias = b_ih[0] + b_hh[0];
    const int nrows = BB * SS;
    for (int r = group; r < nrows; r += ngroups) {
        const float4 v = reinterpret_cast<const float4*>(X + (size_t)r * FF)[lane16];
        float p = v.x * w.x + v.y * w.y + v.z * w.z + v.w * w.w;
        p += __shfl_xor(p, 1);
        p += __shfl_xor(p, 2);
        p += __shfl_xor(p, 4);
        p += __shfl_xor(p, 8);
        if (lane16 == 0) {
            u[r] = TWO_OVER_LN2 * (p + bias);   // rows are [b][t] order already
        }
    }
}

// ---------------------------------------------------------------------------
// K2: the serial scan. lane = batch element (256 lanes total, 4 blocks of 64).
// hx = tanh(z), z = u + W_hh*hx.  Chain kept to 4 dependent ops:
//   r_{t} = rcp(1 + exp2( fma(-2w', r_{t-1}, u'_t + w') )),  hx = 1 - 2r (off-chain)
// where u' = 2log2e*(u+bias) (from K1), w' = 2log2e*W_hh.
// 16-step blocks with one-iteration register prefetch (float4 loads, [b][t]).
// ---------------------------------------------------------------------------
__global__ __launch_bounds__(64) void k_scan(
    const float* __restrict__ u, const float* __restrict__ hx0,
    const float* __restrict__ W_hh, float* __restrict__ out_h)
{
    const int b = blockIdx.x * 64 + threadIdx.x;
    const float wp  = W_hh[0] * TWO_OVER_LN2;
    const float m2w = -2.0f * wp;
    float r = 0.5f * (1.0f - hx0[b]);          // so that 1-2r == hx0
    const float4* ub = reinterpret_cast<const float4*>(u + (size_t)b * SS);

    float cur[16], nxt[16];
    {
        float4 a0 = ub[0], a1 = ub[1], a2 = ub[2], a3 = ub[3];
        cur[0]=a0.x; cur[1]=a0.y; cur[2]=a0.z; cur[3]=a0.w;
        cur[4]=a1.x; cur[5]=a1.y; cur[6]=a1.z; cur[7]=a1.w;
        cur[8]=a2.x; cur[9]=a2.y; cur[10]=a2.z; cur[11]=a2.w;
        cur[12]=a3.x; cur[13]=a3.y; cur[14]=a3.z; cur[15]=a3.w;
    }
    const int NIT = SS / 16;
    for (int i = 0; i < NIT; ++i) {
        const int nb = (i + 1 < NIT) ? (i + 1) : (NIT - 1);
        {   // prefetch next 16 u-values (independent of the chain; issues early)
            float4 a0 = ub[nb*4+0], a1 = ub[nb*4+1], a2 = ub[nb*4+2], a3 = ub[nb*4+3];
            nxt[0]=a0.x; nxt[1]=a0.y; nxt[2]=a0.z; nxt[3]=a0.w;
            nxt[4]=a1.x; nxt[5]=a1.y; nxt[6]=a1.z; nxt[7]=a1.w;
            nxt[8]=a2.x; nxt[9]=a2.y; nxt[10]=a2.z; nxt[11]=a2.w;
            nxt[12]=a3.x; nxt[13]=a3.y; nxt[14]=a3.z; nxt[15]=a3.w;
        }
        float* outp = out_h + (size_t)i * 16 * BB + b;
        #pragma unroll
        for (int j = 0; j < 16; ++j) {
            float z = fmaf(m2w, r, cur[j] + wp);   // cur[j]+wp is off the dep chain
            float y = __builtin_amdgcn_exp2f(z);
            r = __builtin_amdgcn_rcpf(y + 1.0f);
            outp[(size_t)j * BB] = fmaf(-2.0f, r, 1.0f);   // hx (off-chain)
        }
        #pragma unroll
        for (int j = 0; j < 16; ++j) cur[j] = nxt[j];
    }
}

// ---------------------------------------------------------------------------
// K3: lam[t][b] = softplus( sum_j relu( (hx*W2e_j+be_j)*t + (hx*W2o_j+bo_j) ) )
// Fully parallel. thread = (b = tid, 8 consecutive t per block).
// Basis constants staged in LDS as float4 per j; j-loop outer so each
// constant load amortizes over 8 elements.
// ---------------------------------------------------------------------------
__global__ __launch_bounds__(256) void k_lam(
    const float* __restrict__ X, const float* __restrict__ W_h2p,
    const float* __restrict__ b_h2p, const float* __restrict__ hid,
    float* __restrict__ lam)
{
    __shared__ float4 cb[NBB];
    if (threadIdx.x < NBB) {
        int j = threadIdx.x;
        cb[j] = make_float4(W_h2p[2*j], W_h2p[2*j+1], b_h2p[2*j], b_h2p[2*j+1]);
    }
    __syncthreads();

    const int bi = threadIdx.x;           // batch index 0..255
    const int t0 = blockIdx.x * 8;        // 8 consecutive timesteps

    float hx[8], tf[8], s[8];
    #pragma unroll
    for (int k = 0; k < 8; ++k) {
        hx[k] = hid[(size_t)(t0 + k) * BB + bi];                       // coalesced
        tf[k] = X[(size_t)bi * SS * FF + (size_t)(t0 + k) * FF + 1];   // L3-resident
        s[k] = 0.0f;
    }
    for (int j = 0; j < NBB; ++j) {
        const float4 c = cb[j];   // uniform LDS broadcast
        #pragma unroll
        for (int k = 0; k < 8; ++k) {
            float alpha = fmaf(hx[k], c.x, c.z);
            float beta  = fmaf(hx[k], c.y, c.w);
            s[k] += fmaxf(fmaf(alpha, tf[k], beta), 0.0f);
        }
    }
    #pragma unroll
    for (int k = 0; k < 8; ++k) {
        float v  = s[k];
        float as = fabsf(v);
        float e  = __builtin_amdgcn_exp2f(-as * 1.4426950408889634f);
        float l  = __builtin_amdgcn_logf(1.0f + e) * 0.6931471805599453f;
        lam[(size_t)(t0 + k) * BB + bi] = fmaxf(v, 0.0f) + l;          // coalesced
    }
}

// ---------------------------------------------------------------------------
extern "C" void kernel_launch(void* const* d_in, const int* in_sizes, int n_in,
                              void* d_out, int out_size, void* d_ws, size_t ws_size,
                              hipStream_t stream) {
    const float* X     = (const float*)d_in[0];
    const float* hx0   = (const float*)d_in[1];
    const float* W_ih  = (const float*)d_in[2];
    const float* b_ih  = (const float*)d_in[3];
    const float* W_hh  = (const float*)d_in[4];
    const float* b_hh  = (const float*)d_in[5];
    const float* W_h2p = (const float*)d_in[6];
    const float* b_h2p = (const float*)d_in[7];

    float* out_h = (float*)d_out;                 // hidden_states (S,B,1) flat [t][b]
    float* out_l = out_h + (size_t)SS * BB;       // intensity     (S,B)   flat [t][b]
    float* u = (float*)d_ws;                      // u' [B][S], 4 MiB scratch

    k_proj<<<2048, 256, 0, stream>>>(X, W_ih, b_ih, b_hh, u);
    k_scan<<<4, 64, 0, stream>>>(u, hx0, W_hh, out_h);
    k_lam<<<SS / 8, 256, 0, stream>>>(X, W_h2p, b_h2p, out_h, out_l);
}

// Round 2
// 78.250 us; speedup vs baseline: 1.4905x; 1.4905x over previous
//
#include <hip/hip_runtime.h>

#define BB 256
#define SS 2048
#define FF 64
#define NBB 32

// 2*log2(e): folded into u so the scan's tanh needs only exp2 (no extra mul on chain)
#define TWO_OVER_LN2 2.885390081777927f

// ---------------------------------------------------------------------------
// K1: u[b][t] = 2log2e * ( dot(X[b,t,:], W_ih) + b_ih + b_hh ) + 2log2e*W_hh
// (the +w' constant of the scan's exponent is folded in here).
// Also compacts tf[b][t] = X[b,t,1] for K3.
// 16 lanes per row (float4 each), butterfly-reduce, lane0 writes.
// ---------------------------------------------------------------------------
__global__ __launch_bounds__(256) void k_proj(
    const float* __restrict__ X, const float* __restrict__ W_ih,
    const float* __restrict__ b_ih, const float* __restrict__ b_hh,
    const float* __restrict__ W_hh,
    float* __restrict__ u, float* __restrict__ tf)
{
    const int lane16 = threadIdx.x & 15;
    const int group  = (blockIdx.x * blockDim.x + threadIdx.x) >> 4;
    const int ngroups = (gridDim.x * blockDim.x) >> 4;
    const float4 w = reinterpret_cast<const float4*>(W_ih)[lane16];
    const float bias = b_ih[0] + b_hh[0];
    const float wp = W_hh[0] * TWO_OVER_LN2;
    const int nrows = BB * SS;
    for (int r = group; r < nrows; r += ngroups) {
        const float4 v = reinterpret_cast<const float4*>(X + (size_t)r * FF)[lane16];
        float p = v.x * w.x + v.y * w.y + v.z * w.z + v.w * w.w;
        p += __shfl_xor(p, 1);
        p += __shfl_xor(p, 2);
        p += __shfl_xor(p, 4);
        p += __shfl_xor(p, 8);
        if (lane16 == 0) {
            u[r] = TWO_OVER_LN2 * (p + bias) + wp;   // rows are [b][t] order
            tf[r] = v.y;                             // X[b,t,1] compacted
        }
    }
}

// ---------------------------------------------------------------------------
// K2: the serial scan. lane = batch element (256 lanes total, 4 blocks of 64).
// hx = tanh(z), z = u + W_hh*hx.  Chain kept to 4 dependent ops:
//   r_t = rcp(1 + exp2( fma(-2w', r_{t-1}, u''_t) )),  hx = 1 - 2r (off-chain)
// where u'' = 2log2e*(u+bias) + w' (all folded in K1), w' = 2log2e*W_hh.
// Distance-2 prefetch: 3 rotating 4xfloat4 buffers, outer loop unrolled x3 so
// no buffer copies force early vmcnt waits (~1100cy slack > ~900cy HBM lat).
// ---------------------------------------------------------------------------
#define LOADU(B0,B1,B2,B3, idx) { \
    const int nb_ = (idx) < NIT ? (idx) : (NIT - 1); \
    B0 = ub[nb_*4+0]; B1 = ub[nb_*4+1]; B2 = ub[nb_*4+2]; B3 = ub[nb_*4+3]; }

#define STEP(c) { \
    float z = fmaf(m2w, r, (c)); \
    float y = __builtin_amdgcn_exp2f(z); \
    r = __builtin_amdgcn_rcpf(y + 1.0f); \
    *op = fmaf(-2.0f, r, 1.0f); op += BB; }

#define PROCESS(B0,B1,B2,B3) { \
    STEP(B0.x) STEP(B0.y) STEP(B0.z) STEP(B0.w) \
    STEP(B1.x) STEP(B1.y) STEP(B1.z) STEP(B1.w) \
    STEP(B2.x) STEP(B2.y) STEP(B2.z) STEP(B2.w) \
    STEP(B3.x) STEP(B3.y) STEP(B3.z) STEP(B3.w) }

__global__ __launch_bounds__(64) void k_scan(
    const float* __restrict__ u, const float* __restrict__ hx0,
    const float* __restrict__ W_hh, float* __restrict__ out_h)
{
    const int b = blockIdx.x * 64 + threadIdx.x;
    const float wp  = W_hh[0] * TWO_OVER_LN2;
    const float m2w = -2.0f * wp;
    float r = 0.5f * (1.0f - hx0[b]);          // so that 1-2r == hx0
    const float4* ub = reinterpret_cast<const float4*>(u + (size_t)b * SS);
    float* op = out_h + b;

    const int NIT = SS / 16;                   // 128 iterations of 16 steps
    float4 A0,A1,A2,A3, B0,B1,B2,B3, C0,C1,C2,C3;
    LOADU(A0,A1,A2,A3, 0)
    LOADU(B0,B1,B2,B3, 1)
    int i = 0;
    #pragma unroll 1
    for (int g = 0; g < 42; ++g) {             // 42*3 = 126 iterations
        LOADU(C0,C1,C2,C3, i+2) PROCESS(A0,A1,A2,A3)
        LOADU(A0,A1,A2,A3, i+3) PROCESS(B0,B1,B2,B3)
        LOADU(B0,B1,B2,B3, i+4) PROCESS(C0,C1,C2,C3)
        i += 3;
    }
    PROCESS(A0,A1,A2,A3)                        // iteration 126
    PROCESS(B0,B1,B2,B3)                        // iteration 127
}

// ---------------------------------------------------------------------------
// K3: lam[t][b] = softplus( sum_j relu( (hx*W2e_j+be_j)*t + (hx*W2o_j+bo_j) ) )
// Fully parallel. thread = (b = tid, 8 consecutive t per block).
// tf comes compacted from K1 (two float4 loads/thread, L2-resident).
// ---------------------------------------------------------------------------
__global__ __launch_bounds__(256) void k_lam(
    const float* __restrict__ tf, const float* __restrict__ W_h2p,
    const float* __restrict__ b_h2p, const float* __restrict__ hid,
    float* __restrict__ lam)
{
    __shared__ float4 cb[NBB];
    if (threadIdx.x < NBB) {
        int j = threadIdx.x;
        cb[j] = make_float4(W_h2p[2*j], W_h2p[2*j+1], b_h2p[2*j], b_h2p[2*j+1]);
    }
    __syncthreads();

    const int bi = threadIdx.x;           // batch index 0..255
    const int t0 = blockIdx.x * 8;        // 8 consecutive timesteps

    float hx[8], tt[8], s[8];
    {
        const float4* tb = reinterpret_cast<const float4*>(tf + (size_t)bi * SS + t0);
        float4 ta = tb[0], tc = tb[1];
        tt[0]=ta.x; tt[1]=ta.y; tt[2]=ta.z; tt[3]=ta.w;
        tt[4]=tc.x; tt[5]=tc.y; tt[6]=tc.z; tt[7]=tc.w;
    }
    #pragma unroll
    for (int k = 0; k < 8; ++k) {
        hx[k] = hid[(size_t)(t0 + k) * BB + bi];                       // coalesced
        s[k] = 0.0f;
    }
    for (int j = 0; j < NBB; ++j) {
        const float4 c = cb[j];   // uniform LDS broadcast
        #pragma unroll
        for (int k = 0; k < 8; ++k) {
            float alpha = fmaf(hx[k], c.x, c.z);
            float beta  = fmaf(hx[k], c.y, c.w);
            s[k] += fmaxf(fmaf(alpha, tt[k], beta), 0.0f);
        }
    }
    #pragma unroll
    for (int k = 0; k < 8; ++k) {
        float v  = s[k];
        float as = fabsf(v);
        float e  = __builtin_amdgcn_exp2f(-as * 1.4426950408889634f);
        float l  = __builtin_amdgcn_logf(1.0f + e) * 0.6931471805599453f;
        lam[(size_t)(t0 + k) * BB + bi] = fmaxf(v, 0.0f) + l;          // coalesced
    }
}

// ---------------------------------------------------------------------------
extern "C" void kernel_launch(void* const* d_in, const int* in_sizes, int n_in,
                              void* d_out, int out_size, void* d_ws, size_t ws_size,
                              hipStream_t stream) {
    const float* X     = (const float*)d_in[0];
    const float* hx0   = (const float*)d_in[1];
    const float* W_ih  = (const float*)d_in[2];
    const float* b_ih  = (const float*)d_in[3];
    const float* W_hh  = (const float*)d_in[4];
    const float* b_hh  = (const float*)d_in[5];
    const float* W_h2p = (const float*)d_in[6];
    const float* b_h2p = (const float*)d_in[7];

    float* out_h = (float*)d_out;                 // hidden_states (S,B,1) flat [t][b]
    float* out_l = out_h + (size_t)SS * BB;       // intensity     (S,B)   flat [t][b]
    float* u  = (float*)d_ws;                     // u'' [B][S], 2 MiB
    float* tf = u + (size_t)BB * SS;              // X[:,:,1] compacted, 2 MiB

    k_proj<<<2048, 256, 0, stream>>>(X, W_ih, b_ih, b_hh, W_hh, u, tf);
    k_scan<<<4, 64, 0, stream>>>(u, hx0, W_hh, out_h);
    k_lam<<<SS / 8, 256, 0, stream>>>(tf, W_h2p, b_h2p, out_h, out_l);
}